// Round 13
// baseline (104.075 us; speedup 1.0000x reference)
//
#include <hip/hip_runtime.h>
#include <stdint.h>

typedef float  f32x4  __attribute__((ext_vector_type(4)));
typedef float  f32x16 __attribute__((ext_vector_type(16)));
typedef short  s16x8  __attribute__((ext_vector_type(8)));
typedef unsigned short u16x4 __attribute__((ext_vector_type(4)));

#define LPAD 2052   // L + 4 padded positions per batch row

__device__ __forceinline__ float bf2f(unsigned short u){
  unsigned v = ((unsigned)u) << 16;
  return __builtin_bit_cast(float, v);
}
__device__ __forceinline__ unsigned short f2bf(float f){
  unsigned u = __builtin_bit_cast(unsigned, f);
  u += 0x7fffu + ((u >> 16) & 1u);
  return (unsigned short)(u >> 16);
}
__device__ __forceinline__ unsigned cvt_pk_bf16(float lo, float hi){
  unsigned r;
  asm volatile("v_cvt_pk_bf16_f32 %0, %1, %2" : "=v"(r) : "v"(lo), "v"(hi));
  return r;
}

// ---------------- K_prep: Wd fp32->bf16 (b<1024) | eye pads (b<1152) | Wa2g (else) ----
__global__ void k_prep(const float* __restrict__ Wd, unsigned short* __restrict__ Wbf,
                       unsigned short* __restrict__ H,
                       const float* __restrict__ Wa, unsigned short* __restrict__ Wa2g){
  const int b = blockIdx.x;
  if (b < 1024){
    int i = b * 256 + threadIdx.x;           // 262144 f32x4 chunks
    f32x4 v = ((const f32x4*)Wd)[i];
    u16x4 o;
    o[0] = f2bf(v[0]); o[1] = f2bf(v[1]); o[2] = f2bf(v[2]); o[3] = f2bf(v[3]);
    ((u16x4*)Wbf)[i] = o;
  } else if (b < 1152){
    int t = (b - 1024) * 256 + threadIdx.x;  // 32768
    int bt = t >> 12;
    int r = t & 4095;
    int which = r >> 10;
    int ij = r & 1023;
    int p = (which < 2) ? which : (2048 + which);
    H[((size_t)(bt * LPAD + p) << 10) + ij] = ((ij >> 5) == (ij & 31)) ? 0x3F80 : 0;
  } else {
    int t = (b - 1152) * 256 + threadIdx.x;  // 32768 = 32*1024
    int col = t >> 10, e = t & 1023;
    int f = col / 5, kk = col - 5 * f;
    unsigned short v = 0;
    if (col < 25) v = f2bf(Wa[f * 5120 + e * 5 + kk]);
    Wa2g[t] = v;
  }
}

#define MFMA16 __builtin_amdgcn_mfma_f32_16x16x32_bf16

// ---------------- K1: 256x128 tile, A staged as FP32 (cvt fused), 80KB LDS, 2 blocks/CU ----
// A region: 64KB fp32 (rows 256B, 16B chunk c stored at c^(row&7)); B: 16KB bf16 (r12 layout).
// Loop shape identical to r12's proven kernel: stage -> sync -> read+cvt+MFMA -> sync.
__global__ __launch_bounds__(512, 4) void k_gemm2f(const float* __restrict__ X,         // [16384][1024] fp32
                                                   const unsigned short* __restrict__ Bw,// [1024][1024] bf16
                                                   const float* __restrict__ bias,
                                                   unsigned short* __restrict__ H){
  __shared__ __align__(128) unsigned short lds[40960];  // 80KB: A fp32 64KB | B bf16 16KB
  const int tid = threadIdx.x;
  const int wid = tid >> 6, l = tid & 63;
  const int wm = wid >> 1, wn = wid & 1;     // 4x2 waves; wave tile 64x64
  const int lm = l & 15, lk = l >> 4;
  const int hb = blockIdx.x;                 // 0..511
  const int xcd = hb & 7, sl = hb >> 3;      // 0..63
  const int bm = xcd * 8 + (sl >> 3), bn = sl & 7;
  const int M0 = bm * 256, N0 = bn * 128;

  const unsigned koB0 = (unsigned)((lk ^ (lm & 7)) << 4);   // B swizzled k-chunk (bf16 rows)
  const unsigned koB1 = koB0 ^ 64u;
  const unsigned rBb = 65536u + ((unsigned)(wn * 64 + lm)) * 128u;  // + n*2048

  f32x4 acc[4][4] = {};

  for (int kt = 0; kt < 16; ++kt){
    const int ktK = kt * 64;
    // stage A fp32: 64KB, 8 x 16B per thread; linear LDS dest, inverse-swizzled source
    #pragma unroll
    for (int j = 0; j < 8; j++){
      unsigned d = (unsigned)(j * 512 + tid) * 16;
      unsigned row = d >> 8;                          // 256B rows
      unsigned cs = ((d >> 4) & 15u) ^ (row & 7u);    // 16B chunk, XOR low 3 bits
      const float* g = X + (size_t)(M0 + row) * 1024 + ktK + cs * 4u;
      __builtin_amdgcn_global_load_lds((const __attribute__((address_space(1))) void*)g,
                                       (__attribute__((address_space(3))) void*)&lds[d >> 1],
                                       16, 0, 0);
    }
    // stage B bf16: 16KB, 2 x 16B per thread
    #pragma unroll
    for (int j = 0; j < 2; j++){
      unsigned db = (unsigned)(j * 512 + tid) * 16;
      unsigned row = db >> 7;                         // 128B rows
      unsigned cs = ((db >> 4) & 7u) ^ (row & 7u);
      const unsigned short* g = Bw + (size_t)(N0 + row) * 1024 + ktK + cs * 8u;
      __builtin_amdgcn_global_load_lds((const __attribute__((address_space(1))) void*)g,
                                       (__attribute__((address_space(3))) void*)&lds[(65536u + db) >> 1],
                                       16, 0, 0);
    }
    __syncthreads();   // vmcnt(0) drain; covered by co-resident block's compute

    s16x8 b0[4], b1[4];
    #pragma unroll
    for (int n = 0; n < 4; n++){
      b0[n] = *(const s16x8*)&lds[(rBb + n * 2048u + koB0) >> 1];
      b1[n] = *(const s16x8*)&lds[(rBb + n * 2048u + koB1) >> 1];
    }
    #pragma unroll
    for (int m = 0; m < 4; m++){
      unsigned rr = (unsigned)(wm * 64 + m * 16 + lm);
      unsigned base = rr * 256u;
      unsigned r7 = rr & 7u;
      #pragma unroll
      for (int h = 0; h < 2; h++){
        unsigned c0 = ((unsigned)(h * 8 + 2 * lk))     ^ r7;
        unsigned c1 = ((unsigned)(h * 8 + 2 * lk + 1)) ^ r7;
        f32x4 lo = *(const f32x4*)&lds[(base + c0 * 16u) >> 1];
        f32x4 hi = *(const f32x4*)&lds[(base + c1 * 16u) >> 1];
        union { unsigned u[4]; s16x8 v; } af;
        af.u[0] = cvt_pk_bf16(lo[0], lo[1]);
        af.u[1] = cvt_pk_bf16(lo[2], lo[3]);
        af.u[2] = cvt_pk_bf16(hi[0], hi[1]);
        af.u[3] = cvt_pk_bf16(hi[2], hi[3]);
        #pragma unroll
        for (int n = 0; n < 4; n++)
          acc[m][n] = MFMA16(af.v, (h == 0) ? b0[n] : b1[n], acc[m][n], 0, 0, 0);
      }
    }
    __syncthreads();
  }

  // epilogue: h = acc + bias -> bf16 H
  float bv[4];
  #pragma unroll
  for (int n = 0; n < 4; n++) bv[n] = bias[N0 + wn * 64 + n * 16 + lm];
  #pragma unroll
  for (int m = 0; m < 4; m++){
    #pragma unroll
    for (int r = 0; r < 4; r++){
      int gm = M0 + wm * 64 + m * 16 + lk * 4 + r;
      int bb = gm >> 11, li = gm & 2047;
      unsigned short* orow = H + ((size_t)(bb * LPAD + 2 + li) << 10);
      #pragma unroll
      for (int n = 0; n < 4; n++){
        orow[N0 + wn * 64 + n * 16 + lm] = f2bf(acc[m][n][r] + bv[n]);
      }
    }
  }
}

// ---------------- K2: part[p][0..31] = <Hpad[p], Wa2g[col]>  (thin MFMA GEMM) ----------------
__global__ __launch_bounds__(256) void k_part(const unsigned short* __restrict__ H,    // [16416][1024]
                                              const unsigned short* __restrict__ Wa2g, // [32][1024]
                                              float* __restrict__ part){               // [16512][32]
  __shared__ unsigned short sB[32768];  // [32 col][1024 k], chunk c at c^(col&7)
  const int tid = threadIdx.x;
  const int wv = tid >> 6, l = tid & 63;
  const int lm = l & 15, lk = l >> 4;
  #pragma unroll
  for (int j = 0; j < 16; j++){
    unsigned d = (unsigned)(j * 256 + tid) * 16;
    unsigned col = d >> 11;
    unsigned srcC = ((d >> 4) & 127u) ^ (col & 7u);
    const unsigned short* g = Wa2g + col * 1024 + srcC * 8;
    __builtin_amdgcn_global_load_lds((const __attribute__((address_space(1))) void*)g,
                                     (__attribute__((address_space(3))) void*)&sB[d >> 1],
                                     16, 0, 0);
  }
  __syncthreads();
  const int rbase = blockIdx.x * 128 + wv * 32;
  f32x4 acc[2][2] = {};
  for (int kk = 0; kk < 1024; kk += 32){
    s16x8 aF[2], bF[2];
    #pragma unroll
    for (int m = 0; m < 2; m++)
      aF[m] = *(const s16x8*)(H + (size_t)(rbase + m * 16 + lm) * 1024 + kk + lk * 8);
    #pragma unroll
    for (int n = 0; n < 2; n++){
      unsigned col = (unsigned)(n * 16 + lm);
      unsigned c = (unsigned)(kk >> 3) + (unsigned)lk;
      bF[n] = *(const s16x8*)&sB[(col * 2048u + ((c ^ (col & 7u)) << 4)) >> 1];
    }
    #pragma unroll
    for (int m = 0; m < 2; m++){
      #pragma unroll
      for (int n = 0; n < 2; n++)
        acc[m][n] = MFMA16(aF[m], bF[n], acc[m][n], 0, 0, 0);
    }
  }
  #pragma unroll
  for (int m = 0; m < 2; m++){
    #pragma unroll
    for (int r = 0; r < 4; r++){
      int row = rbase + m * 16 + lk * 4 + r;
      #pragma unroll
      for (int n = 0; n < 2; n++)
        part[(size_t)row * 32 + n * 16 + lm] = acc[m][n][r];
    }
  }
}

// ---------------- K4: softmax (from part) + 32x32 matrix chain, scaled by s ----------------
__global__ __launch_bounds__(256) void k_chain(const unsigned short* __restrict__ H,
                                               const float* __restrict__ part,
                                               const float* __restrict__ battn,
                                               float* __restrict__ out){
  const int tid = threadIdx.x;
  const int w = tid >> 6, l = tid & 63;
  const int blk = (blockIdx.x & 7) * 512 + (blockIdx.x >> 3);
  const int pos = blk * 4 + w;
  const int bb = pos >> 11, li = pos & 2047;
  const unsigned short* hbase = H + ((size_t)(bb * LPAD + li) << 10);
  const int col = l & 31;
  const int kh = (l >> 5) << 3;

  const float* prow = part + (size_t)(bb * LPAD + li) * 32;
  float sc[5];
  #pragma unroll
  for (int f = 0; f < 5; f++){
    float a = battn[f];
    #pragma unroll
    for (int k = 0; k < 5; k++)
      a += prow[k * 32 + f * 5 + k];
    sc[f] = (a > 0.f) ? a : 0.01f * a;
  }
  float mx = sc[0];
  #pragma unroll
  for (int f = 1; f < 5; f++) mx = fmaxf(mx, sc[f]);
  float e0 = expf(sc[0] - mx), e1 = expf(sc[1] - mx), e2 = expf(sc[2] - mx),
        e3 = expf(sc[3] - mx), e4 = expf(sc[4] - mx);
  float ssum = e0 + e1 + e2 + e3 + e4;
  float inv = 1.f / ssum;
  float inv2 = inv * inv;
  const float sv = (e0 * e1 * e2 * e3 * e4) * inv2 * inv2 * inv;

  const unsigned short* h4 = hbase + 4 * 1024;
  unsigned q0, q1, q2, q3, q4, q5, q6, q7;
  {
    #define LD2(kk) ((unsigned)h4[(kk) * 32 + col] | ((unsigned)h4[((kk) + 1) * 32 + col] << 16))
    q0 = LD2(kh + 0);  q1 = LD2(kh + 2);  q2 = LD2(kh + 4);  q3 = LD2(kh + 6);
    q4 = LD2(kh + 16); q5 = LD2(kh + 18); q6 = LD2(kh + 20); q7 = LD2(kh + 22);
    #undef LD2
  }
  union { unsigned u[4]; s16x8 v; } ub0, ub1;
  ub0.u[0] = q0; ub0.u[1] = q1; ub0.u[2] = q2; ub0.u[3] = q3;
  ub1.u[0] = q4; ub1.u[1] = q5; ub1.u[2] = q6; ub1.u[3] = q7;
  s16x8 Bf0 = ub0.v, Bf1 = ub1.v;

  f32x16 acc;
  #pragma unroll
  for (int st = 0; st < 4; st++){
    const int km = 3 - st;
    const unsigned short* hA = hbase + (km << 10);
    s16x8 A0 = *(const s16x8*)(hA + col * 32 + kh);
    s16x8 A1 = *(const s16x8*)(hA + col * 32 + kh + 16);
    f32x16 z = {0,0,0,0,0,0,0,0,0,0,0,0,0,0,0,0};
    acc = __builtin_amdgcn_mfma_f32_32x32x16_bf16(A0, Bf0, z,   0, 0, 0);
    acc = __builtin_amdgcn_mfma_f32_32x32x16_bf16(A1, Bf1, acc, 0, 0, 0);
    if (st < 3){
      unsigned d0 = cvt_pk_bf16(acc[0],  acc[1]);
      unsigned d1 = cvt_pk_bf16(acc[2],  acc[3]);
      unsigned d2 = cvt_pk_bf16(acc[4],  acc[5]);
      unsigned d3 = cvt_pk_bf16(acc[6],  acc[7]);
      unsigned d4 = cvt_pk_bf16(acc[8],  acc[9]);
      unsigned d5 = cvt_pk_bf16(acc[10], acc[11]);
      unsigned d6 = cvt_pk_bf16(acc[12], acc[13]);
      unsigned d7 = cvt_pk_bf16(acc[14], acc[15]);
      unsigned p0 = __shfl_xor(d0, 32, 64);
      unsigned p1 = __shfl_xor(d1, 32, 64);
      unsigned p2 = __shfl_xor(d2, 32, 64);
      unsigned p3 = __shfl_xor(d3, 32, 64);
      unsigned p4 = __shfl_xor(d4, 32, 64);
      unsigned p5 = __shfl_xor(d5, 32, 64);
      unsigned p6 = __shfl_xor(d6, 32, 64);
      unsigned p7 = __shfl_xor(d7, 32, 64);
      const bool lo = (l < 32);
      ub0.u[0] = lo ? d0 : p2;  ub0.u[1] = lo ? d1 : p3;
      ub0.u[2] = lo ? p0 : d2;  ub0.u[3] = lo ? p1 : d3;
      ub1.u[0] = lo ? d4 : p6;  ub1.u[1] = lo ? d5 : p7;
      ub1.u[2] = lo ? p4 : d6;  ub1.u[3] = lo ? p5 : d7;
      Bf0 = ub0.v; Bf1 = ub1.v;
    }
  }

  float* ob = out + ((size_t)pos << 10);
  #pragma unroll
  for (int t = 0; t < 16; t++){
    int row = (t & 3) + 8 * (t >> 2) + ((l >> 5) << 2);
    ob[row * 32 + col] = sv * acc[t];
  }
}

// ---------------- launcher ----------------
extern "C" void kernel_launch(void* const* d_in, const int* in_sizes, int n_in,
                              void* d_out, int out_size, void* d_ws, size_t ws_size,
                              hipStream_t stream){
  const float* X  = (const float*)d_in[0];   // [8][2048][32][32] fp32
  const float* Wd = (const float*)d_in[1];
  const float* bd = (const float*)d_in[2];
  const float* Wa = (const float*)d_in[3];
  const float* ba = (const float*)d_in[4];
  float* out = (float*)d_out;

  char* ws = (char*)d_ws;
  unsigned short* Hpad = (unsigned short*)ws;                               // 33,619,968 B
  unsigned short* Wbf  = (unsigned short*)(ws + 33619968);                  // 2,097,152 B
  unsigned short* Wa2g = (unsigned short*)(ws + 33619968 + 2097152);        // 65,536 B
  float*          part = (float*)(ws + 33619968 + 2097152 + 65536);         // 2,113,536 B

  k_prep<<<1280, 256, 0, stream>>>(Wd, Wbf, Hpad, Wa, Wa2g);
  k_gemm2f<<<512, 512, 0, stream>>>(X, Wbf, bd, Hpad);
  k_part<<<129, 256, 0, stream>>>(Hpad, Wa2g, part);
  k_chain<<<4096, 256, 0, stream>>>(Hpad, part, ba, out);
}

// Round 14
// 88.979 us; speedup vs baseline: 1.1697x; 1.1697x over previous
//
#include <hip/hip_runtime.h>
#include <stdint.h>

typedef float  f32x4  __attribute__((ext_vector_type(4)));
typedef float  f32x16 __attribute__((ext_vector_type(16)));
typedef short  s16x8  __attribute__((ext_vector_type(8)));
typedef unsigned short u16x4 __attribute__((ext_vector_type(4)));

#define LPAD 2052   // L + 4 padded positions per batch row

__device__ __forceinline__ float bf2f(unsigned short u){
  unsigned v = ((unsigned)u) << 16;
  return __builtin_bit_cast(float, v);
}
__device__ __forceinline__ unsigned short f2bf(float f){
  unsigned u = __builtin_bit_cast(unsigned, f);
  u += 0x7fffu + ((u >> 16) & 1u);
  return (unsigned short)(u >> 16);
}
__device__ __forceinline__ unsigned cvt_pk_bf16(float lo, float hi){
  unsigned r;
  asm volatile("v_cvt_pk_bf16_f32 %0, %1, %2" : "=v"(r) : "v"(lo), "v"(hi));
  return r;
}

// ---------------- K_prep: one launch for all preprocessing ----------------
// b < 16384          : X fp32->bf16 (XCD-aligned row remap)
// 16384 <= b < 17408 : Wd fp32->bf16
// 17408 <= b < 17536 : identity pad matrices into H
// else               : Wa2g transpose/pack
__global__ void k_prep(const float* __restrict__ X, unsigned short* __restrict__ Xbf,
                       const float* __restrict__ Wd, unsigned short* __restrict__ Wbf,
                       unsigned short* __restrict__ H,
                       const float* __restrict__ Wa, unsigned short* __restrict__ Wa2g){
  const int b = blockIdx.x;
  if (b < 16384){
    int bb = (b & 7) * 2048 + (b >> 3);        // bijective row remap
    int i = bb * 256 + threadIdx.x;
    f32x4 v = ((const f32x4*)X)[i];
    u16x4 o;
    o[0] = f2bf(v[0]); o[1] = f2bf(v[1]); o[2] = f2bf(v[2]); o[3] = f2bf(v[3]);
    ((u16x4*)Xbf)[i] = o;
  } else if (b < 17408){
    int i = (b - 16384) * 256 + threadIdx.x;   // 262144 f32x4 chunks
    f32x4 v = ((const f32x4*)Wd)[i];
    u16x4 o;
    o[0] = f2bf(v[0]); o[1] = f2bf(v[1]); o[2] = f2bf(v[2]); o[3] = f2bf(v[3]);
    ((u16x4*)Wbf)[i] = o;
  } else if (b < 17536){
    int t = (b - 17408) * 256 + threadIdx.x;   // 32768
    int bt = t >> 12;
    int r = t & 4095;
    int which = r >> 10;
    int ij = r & 1023;
    int p = (which < 2) ? which : (2048 + which);
    H[((size_t)(bt * LPAD + p) << 10) + ij] = ((ij >> 5) == (ij & 31)) ? 0x3F80 : 0;
  } else {
    int t = (b - 17536) * 256 + threadIdx.x;   // 32768 = 32*1024
    int col = t >> 10, e = t & 1023;
    int f = col / 5, kk = col - 5 * f;
    unsigned short v = 0;
    if (col < 25) v = f2bf(Wa[f * 5120 + e * 5 + kk]);
    Wa2g[t] = v;
  }
}

#define MFMA16 __builtin_amdgcn_mfma_f32_16x16x32_bf16

// ---------------- K1: 256x128 tile, 48KB single-buffer LDS, 2 blocks/CU (TLP) ----
// Mechanism: with 2 independent blocks per CU, one block's vmcnt(0)+barrier drain
// is covered by the other block's MFMA phases (m97/m114 implicit overlap).
__global__ __launch_bounds__(512, 4) void k_gemm2(const unsigned short* __restrict__ A,   // [16384][1024]
                                                  const unsigned short* __restrict__ Bw,  // [1024][1024]
                                                  const float* __restrict__ bias,
                                                  unsigned short* __restrict__ H){
  __shared__ __align__(128) unsigned short lds[24576];  // 48KB: A 32KB | B 16KB
  const int tid = threadIdx.x;
  const int wid = tid >> 6, l = tid & 63;
  const int wm = wid >> 1, wn = wid & 1;     // 4x2 wave grid; wave tile 64x64
  const int lm = l & 15, lk = l >> 4;
  const int hb = blockIdx.x;                 // 0..511
  const int xcd = hb & 7, sl = hb >> 3;      // 0..63
  const int bm = xcd * 8 + (sl >> 3), bn = sl & 7;
  const int M0 = bm * 256, N0 = bn * 128;

  // swizzle: 16B chunk c of 128B row stored at chunk c ^ (row&7)  [proven 0-conflict]
  const unsigned ko0 = (unsigned)((lk ^ (lm & 7)) << 4);
  const unsigned ko1 = ko0 ^ 64u;
  const unsigned rA = ((unsigned)(wm * 64 + lm)) * 128u;           // + m*2048
  const unsigned rB = 32768u + ((unsigned)(wn * 64 + lm)) * 128u;  // + n*2048

  f32x4 acc[4][4] = {};

  for (int kt = 0; kt < 16; ++kt){
    const int ktK = kt * 64;
    #pragma unroll
    for (int j = 0; j < 6; j++){
      unsigned d = (unsigned)(j * 512 + tid) * 16;
      const unsigned short* g;
      if (j < 4){                                   // A region: 32KB
        unsigned row = d >> 7;
        unsigned srcC = ((d >> 4) & 7u) ^ (row & 7u);
        g = A + (size_t)(M0 + row) * 1024 + ktK + srcC * 8;
      } else {                                      // B region: 16KB
        unsigned db = d - 32768u;
        unsigned row = db >> 7;
        unsigned srcC = ((db >> 4) & 7u) ^ (row & 7u);
        g = Bw + (size_t)(N0 + row) * 1024 + ktK + srcC * 8;
      }
      __builtin_amdgcn_global_load_lds((const __attribute__((address_space(1))) void*)g,
                                       (__attribute__((address_space(3))) void*)&lds[d >> 1],
                                       16, 0, 0);
    }
    __syncthreads();   // drains vmcnt(0): tile visible (stall covered by co-resident block)

    s16x8 a0[4], b0[4];   // one shared frag set, reused across K-halves (reg cap)
    #pragma unroll
    for (int m = 0; m < 4; m++) a0[m] = *(const s16x8*)&lds[(rA + m * 2048u + ko0) >> 1];
    #pragma unroll
    for (int n = 0; n < 4; n++) b0[n] = *(const s16x8*)&lds[(rB + n * 2048u + ko0) >> 1];
    #pragma unroll
    for (int m = 0; m < 4; m++){
      #pragma unroll
      for (int n = 0; n < 4; n++)
        acc[m][n] = MFMA16(a0[m], b0[n], acc[m][n], 0, 0, 0);
    }
    #pragma unroll
    for (int m = 0; m < 4; m++) a0[m] = *(const s16x8*)&lds[(rA + m * 2048u + ko1) >> 1];
    #pragma unroll
    for (int n = 0; n < 4; n++) b0[n] = *(const s16x8*)&lds[(rB + n * 2048u + ko1) >> 1];
    #pragma unroll
    for (int m = 0; m < 4; m++){
      #pragma unroll
      for (int n = 0; n < 4; n++)
        acc[m][n] = MFMA16(a0[m], b0[n], acc[m][n], 0, 0, 0);
    }
    __syncthreads();   // all reads done before next stage overwrites
  }

  // epilogue: h = acc + bias -> bf16 H
  float bv[4];
  #pragma unroll
  for (int n = 0; n < 4; n++) bv[n] = bias[N0 + wn * 64 + n * 16 + lm];
  #pragma unroll
  for (int m = 0; m < 4; m++){
    #pragma unroll
    for (int r = 0; r < 4; r++){
      int gm = M0 + wm * 64 + m * 16 + lk * 4 + r;
      int bb = gm >> 11, li = gm & 2047;
      unsigned short* orow = H + ((size_t)(bb * LPAD + 2 + li) << 10);
      #pragma unroll
      for (int n = 0; n < 4; n++){
        orow[N0 + wn * 64 + n * 16 + lm] = f2bf(acc[m][n][r] + bv[n]);
      }
    }
  }
}

// ---------------- K2: part[p][0..31] = <Hpad[p], Wa2g[col]>  (thin MFMA GEMM) ----------------
__global__ __launch_bounds__(256) void k_part(const unsigned short* __restrict__ H,    // [16416][1024]
                                              const unsigned short* __restrict__ Wa2g, // [32][1024]
                                              float* __restrict__ part){               // [16512][32]
  __shared__ unsigned short sB[32768];  // [32 col][1024 k], chunk c at c^(col&7)
  const int tid = threadIdx.x;
  const int wv = tid >> 6, l = tid & 63;
  const int lm = l & 15, lk = l >> 4;
  #pragma unroll
  for (int j = 0; j < 16; j++){
    unsigned d = (unsigned)(j * 256 + tid) * 16;
    unsigned col = d >> 11;
    unsigned srcC = ((d >> 4) & 127u) ^ (col & 7u);
    const unsigned short* g = Wa2g + col * 1024 + srcC * 8;
    __builtin_amdgcn_global_load_lds((const __attribute__((address_space(1))) void*)g,
                                     (__attribute__((address_space(3))) void*)&sB[d >> 1],
                                     16, 0, 0);
  }
  __syncthreads();
  const int rbase = blockIdx.x * 128 + wv * 32;
  f32x4 acc[2][2] = {};
  for (int kk = 0; kk < 1024; kk += 32){
    s16x8 aF[2], bF[2];
    #pragma unroll
    for (int m = 0; m < 2; m++)
      aF[m] = *(const s16x8*)(H + (size_t)(rbase + m * 16 + lm) * 1024 + kk + lk * 8);
    #pragma unroll
    for (int n = 0; n < 2; n++){
      unsigned col = (unsigned)(n * 16 + lm);
      unsigned c = (unsigned)(kk >> 3) + (unsigned)lk;
      bF[n] = *(const s16x8*)&sB[(col * 2048u + ((c ^ (col & 7u)) << 4)) >> 1];
    }
    #pragma unroll
    for (int m = 0; m < 2; m++){
      #pragma unroll
      for (int n = 0; n < 2; n++)
        acc[m][n] = MFMA16(aF[m], bF[n], acc[m][n], 0, 0, 0);
    }
  }
  #pragma unroll
  for (int m = 0; m < 2; m++){
    #pragma unroll
    for (int r = 0; r < 4; r++){
      int row = rbase + m * 16 + lk * 4 + r;
      #pragma unroll
      for (int n = 0; n < 2; n++)
        part[(size_t)row * 32 + n * 16 + lm] = acc[m][n][r];
    }
  }
}

// ---------------- K4: softmax (from part) + 32x32 matrix chain, scaled by s ----------------
__global__ __launch_bounds__(256) void k_chain(const unsigned short* __restrict__ H,
                                               const float* __restrict__ part,
                                               const float* __restrict__ battn,
                                               float* __restrict__ out){
  const int tid = threadIdx.x;
  const int w = tid >> 6, l = tid & 63;
  const int blk = (blockIdx.x & 7) * 512 + (blockIdx.x >> 3);
  const int pos = blk * 4 + w;
  const int bb = pos >> 11, li = pos & 2047;
  const unsigned short* hbase = H + ((size_t)(bb * LPAD + li) << 10);
  const int col = l & 31;
  const int kh = (l >> 5) << 3;

  const float* prow = part + (size_t)(bb * LPAD + li) * 32;
  float sc[5];
  #pragma unroll
  for (int f = 0; f < 5; f++){
    float a = battn[f];
    #pragma unroll
    for (int k = 0; k < 5; k++)
      a += prow[k * 32 + f * 5 + k];
    sc[f] = (a > 0.f) ? a : 0.01f * a;
  }
  float mx = sc[0];
  #pragma unroll
  for (int f = 1; f < 5; f++) mx = fmaxf(mx, sc[f]);
  float e0 = expf(sc[0] - mx), e1 = expf(sc[1] - mx), e2 = expf(sc[2] - mx),
        e3 = expf(sc[3] - mx), e4 = expf(sc[4] - mx);
  float ssum = e0 + e1 + e2 + e3 + e4;
  float inv = 1.f / ssum;
  float inv2 = inv * inv;
  const float sv = (e0 * e1 * e2 * e3 * e4) * inv2 * inv2 * inv;

  const unsigned short* h4 = hbase + 4 * 1024;
  unsigned q0, q1, q2, q3, q4, q5, q6, q7;
  {
    #define LD2(kk) ((unsigned)h4[(kk) * 32 + col] | ((unsigned)h4[((kk) + 1) * 32 + col] << 16))
    q0 = LD2(kh + 0);  q1 = LD2(kh + 2);  q2 = LD2(kh + 4);  q3 = LD2(kh + 6);
    q4 = LD2(kh + 16); q5 = LD2(kh + 18); q6 = LD2(kh + 20); q7 = LD2(kh + 22);
    #undef LD2
  }
  union { unsigned u[4]; s16x8 v; } ub0, ub1;
  ub0.u[0] = q0; ub0.u[1] = q1; ub0.u[2] = q2; ub0.u[3] = q3;
  ub1.u[0] = q4; ub1.u[1] = q5; ub1.u[2] = q6; ub1.u[3] = q7;
  s16x8 Bf0 = ub0.v, Bf1 = ub1.v;

  f32x16 acc;
  #pragma unroll
  for (int st = 0; st < 4; st++){
    const int km = 3 - st;
    const unsigned short* hA = hbase + (km << 10);
    s16x8 A0 = *(const s16x8*)(hA + col * 32 + kh);
    s16x8 A1 = *(const s16x8*)(hA + col * 32 + kh + 16);
    f32x16 z = {0,0,0,0,0,0,0,0,0,0,0,0,0,0,0,0};
    acc = __builtin_amdgcn_mfma_f32_32x32x16_bf16(A0, Bf0, z,   0, 0, 0);
    acc = __builtin_amdgcn_mfma_f32_32x32x16_bf16(A1, Bf1, acc, 0, 0, 0);
    if (st < 3){
      unsigned d0 = cvt_pk_bf16(acc[0],  acc[1]);
      unsigned d1 = cvt_pk_bf16(acc[2],  acc[3]);
      unsigned d2 = cvt_pk_bf16(acc[4],  acc[5]);
      unsigned d3 = cvt_pk_bf16(acc[6],  acc[7]);
      unsigned d4 = cvt_pk_bf16(acc[8],  acc[9]);
      unsigned d5 = cvt_pk_bf16(acc[10], acc[11]);
      unsigned d6 = cvt_pk_bf16(acc[12], acc[13]);
      unsigned d7 = cvt_pk_bf16(acc[14], acc[15]);
      unsigned p0 = __shfl_xor(d0, 32, 64);
      unsigned p1 = __shfl_xor(d1, 32, 64);
      unsigned p2 = __shfl_xor(d2, 32, 64);
      unsigned p3 = __shfl_xor(d3, 32, 64);
      unsigned p4 = __shfl_xor(d4, 32, 64);
      unsigned p5 = __shfl_xor(d5, 32, 64);
      unsigned p6 = __shfl_xor(d6, 32, 64);
      unsigned p7 = __shfl_xor(d7, 32, 64);
      const bool lo = (l < 32);
      ub0.u[0] = lo ? d0 : p2;  ub0.u[1] = lo ? d1 : p3;
      ub0.u[2] = lo ? p0 : d2;  ub0.u[3] = lo ? p1 : d3;
      ub1.u[0] = lo ? d4 : p6;  ub1.u[1] = lo ? d5 : p7;
      ub1.u[2] = lo ? p4 : d6;  ub1.u[3] = lo ? p5 : d7;
      Bf0 = ub0.v; Bf1 = ub1.v;
    }
  }

  float* ob = out + ((size_t)pos << 10);
  #pragma unroll
  for (int t = 0; t < 16; t++){
    int row = (t & 3) + 8 * (t >> 2) + ((l >> 5) << 2);
    ob[row * 32 + col] = sv * acc[t];
  }
}

// ---------------- launcher ----------------
extern "C" void kernel_launch(void* const* d_in, const int* in_sizes, int n_in,
                              void* d_out, int out_size, void* d_ws, size_t ws_size,
                              hipStream_t stream){
  const float* X  = (const float*)d_in[0];
  const float* Wd = (const float*)d_in[1];
  const float* bd = (const float*)d_in[2];
  const float* Wa = (const float*)d_in[3];
  const float* ba = (const float*)d_in[4];
  float* out = (float*)d_out;

  char* ws = (char*)d_ws;
  unsigned short* Hpad = (unsigned short*)ws;                               // 33,619,968 B
  unsigned short* Wbf  = (unsigned short*)(ws + 33619968);                  // 2,097,152 B
  unsigned short* Wa2g = (unsigned short*)(ws + 33619968 + 2097152);        // 65,536 B
  float*          part = (float*)(ws + 33619968 + 2097152 + 65536);         // 2,113,536 B
  // scratch parked in d_out (consumed by k_gemm2 before k_chain writes):
  unsigned short* Xbf  = (unsigned short*)d_out;                            // [0, 33,554,432)

  k_prep<<<17664, 256, 0, stream>>>(X, Xbf, Wd, Wbf, Hpad, Wa, Wa2g);
  k_gemm2<<<512, 512, 0, stream>>>(Xbf, Wbf, bd, Hpad);
  k_part<<<129, 256, 0, stream>>>(Hpad, Wa2g, part);
  k_chain<<<4096, 256, 0, stream>>>(Hpad, part, ba, out);
}

// Round 15
// 87.794 us; speedup vs baseline: 1.1854x; 1.0135x over previous
//
#include <hip/hip_runtime.h>
#include <stdint.h>

typedef float  f32x4  __attribute__((ext_vector_type(4)));
typedef float  f32x16 __attribute__((ext_vector_type(16)));
typedef short  s16x8  __attribute__((ext_vector_type(8)));
typedef unsigned short u16x4 __attribute__((ext_vector_type(4)));

#define LPAD 2052   // L + 4 padded positions per batch row

__device__ __forceinline__ float bf2f(unsigned short u){
  unsigned v = ((unsigned)u) << 16;
  return __builtin_bit_cast(float, v);
}
__device__ __forceinline__ unsigned short f2bf(float f){
  unsigned u = __builtin_bit_cast(unsigned, f);
  u += 0x7fffu + ((u >> 16) & 1u);
  return (unsigned short)(u >> 16);
}
__device__ __forceinline__ unsigned cvt_pk_bf16(float lo, float hi){
  unsigned r;
  asm volatile("v_cvt_pk_bf16_f32 %0, %1, %2" : "=v"(r) : "v"(lo), "v"(hi));
  return r;
}

// ---------------- K_prep: one launch for all preprocessing ----------------
__global__ void k_prep(const float* __restrict__ X, unsigned short* __restrict__ Xbf,
                       const float* __restrict__ Wd, unsigned short* __restrict__ Wbf,
                       unsigned short* __restrict__ H,
                       const float* __restrict__ Wa, unsigned short* __restrict__ Wa2g){
  const int b = blockIdx.x;
  if (b < 16384){
    int bb = (b & 7) * 2048 + (b >> 3);        // bijective row remap
    int i = bb * 256 + threadIdx.x;
    f32x4 v = ((const f32x4*)X)[i];
    u16x4 o;
    o[0] = f2bf(v[0]); o[1] = f2bf(v[1]); o[2] = f2bf(v[2]); o[3] = f2bf(v[3]);
    ((u16x4*)Xbf)[i] = o;
  } else if (b < 17408){
    int i = (b - 16384) * 256 + threadIdx.x;   // 262144 f32x4 chunks
    f32x4 v = ((const f32x4*)Wd)[i];
    u16x4 o;
    o[0] = f2bf(v[0]); o[1] = f2bf(v[1]); o[2] = f2bf(v[2]); o[3] = f2bf(v[3]);
    ((u16x4*)Wbf)[i] = o;
  } else if (b < 17536){
    int t = (b - 17408) * 256 + threadIdx.x;   // 32768
    int bt = t >> 12;
    int r = t & 4095;
    int which = r >> 10;
    int ij = r & 1023;
    int p = (which < 2) ? which : (2048 + which);
    H[((size_t)(bt * LPAD + p) << 10) + ij] = ((ij >> 5) == (ij & 31)) ? 0x3F80 : 0;
  } else {
    int t = (b - 17536) * 256 + threadIdx.x;   // 32768 = 32*1024
    int col = t >> 10, e = t & 1023;
    int f = col / 5, kk = col - 5 * f;
    unsigned short v = 0;
    if (col < 25) v = f2bf(Wa[f * 5120 + e * 5 + kk]);
    Wa2g[t] = v;
  }
}

#define MFMA16 __builtin_amdgcn_mfma_f32_16x16x32_bf16

// ---------------- K1: 256x128 tile, 48KB single-buffer LDS, 2 blocks/CU (TLP) ----
__global__ __launch_bounds__(512, 4) void k_gemm2(const unsigned short* __restrict__ A,   // [16384][1024]
                                                  const unsigned short* __restrict__ Bw,  // [1024][1024]
                                                  const float* __restrict__ bias,
                                                  unsigned short* __restrict__ H){
  __shared__ __align__(128) unsigned short lds[24576];  // 48KB: A 32KB | B 16KB
  const int tid = threadIdx.x;
  const int wid = tid >> 6, l = tid & 63;
  const int wm = wid >> 1, wn = wid & 1;     // 4x2 wave grid; wave tile 64x64
  const int lm = l & 15, lk = l >> 4;
  const int hb = blockIdx.x;                 // 0..511
  const int xcd = hb & 7, sl = hb >> 3;      // 0..63
  const int bm = xcd * 8 + (sl >> 3), bn = sl & 7;
  const int M0 = bm * 256, N0 = bn * 128;

  const unsigned ko0 = (unsigned)((lk ^ (lm & 7)) << 4);
  const unsigned ko1 = ko0 ^ 64u;
  const unsigned rA = ((unsigned)(wm * 64 + lm)) * 128u;
  const unsigned rB = 32768u + ((unsigned)(wn * 64 + lm)) * 128u;

  f32x4 acc[4][4] = {};

  for (int kt = 0; kt < 16; ++kt){
    const int ktK = kt * 64;
    #pragma unroll
    for (int j = 0; j < 6; j++){
      unsigned d = (unsigned)(j * 512 + tid) * 16;
      const unsigned short* g;
      if (j < 4){
        unsigned row = d >> 7;
        unsigned srcC = ((d >> 4) & 7u) ^ (row & 7u);
        g = A + (size_t)(M0 + row) * 1024 + ktK + srcC * 8;
      } else {
        unsigned db = d - 32768u;
        unsigned row = db >> 7;
        unsigned srcC = ((db >> 4) & 7u) ^ (row & 7u);
        g = Bw + (size_t)(N0 + row) * 1024 + ktK + srcC * 8;
      }
      __builtin_amdgcn_global_load_lds((const __attribute__((address_space(1))) void*)g,
                                       (__attribute__((address_space(3))) void*)&lds[d >> 1],
                                       16, 0, 0);
    }
    __syncthreads();

    s16x8 a0[4], b0[4];
    #pragma unroll
    for (int m = 0; m < 4; m++) a0[m] = *(const s16x8*)&lds[(rA + m * 2048u + ko0) >> 1];
    #pragma unroll
    for (int n = 0; n < 4; n++) b0[n] = *(const s16x8*)&lds[(rB + n * 2048u + ko0) >> 1];
    #pragma unroll
    for (int m = 0; m < 4; m++){
      #pragma unroll
      for (int n = 0; n < 4; n++)
        acc[m][n] = MFMA16(a0[m], b0[n], acc[m][n], 0, 0, 0);
    }
    #pragma unroll
    for (int m = 0; m < 4; m++) a0[m] = *(const s16x8*)&lds[(rA + m * 2048u + ko1) >> 1];
    #pragma unroll
    for (int n = 0; n < 4; n++) b0[n] = *(const s16x8*)&lds[(rB + n * 2048u + ko1) >> 1];
    #pragma unroll
    for (int m = 0; m < 4; m++){
      #pragma unroll
      for (int n = 0; n < 4; n++)
        acc[m][n] = MFMA16(a0[m], b0[n], acc[m][n], 0, 0, 0);
    }
    __syncthreads();
  }

  float bv[4];
  #pragma unroll
  for (int n = 0; n < 4; n++) bv[n] = bias[N0 + wn * 64 + n * 16 + lm];
  #pragma unroll
  for (int m = 0; m < 4; m++){
    #pragma unroll
    for (int r = 0; r < 4; r++){
      int gm = M0 + wm * 64 + m * 16 + lk * 4 + r;
      int bb = gm >> 11, li = gm & 2047;
      unsigned short* orow = H + ((size_t)(bb * LPAD + 2 + li) << 10);
      #pragma unroll
      for (int n = 0; n < 4; n++){
        orow[N0 + wn * 64 + n * 16 + lm] = f2bf(acc[m][n][r] + bv[n]);
      }
    }
  }
}

// ---------------- K2: part[p][0..31] = <Hpad[p], Wa2g[col]> (thin MFMA GEMM) ----------------
// 258 blocks x 128 threads (2 waves x 32 rows): full 256-CU coverage (was 129 blocks = half idle).
__global__ __launch_bounds__(128) void k_part(const unsigned short* __restrict__ H,    // [16416][1024]
                                              const unsigned short* __restrict__ Wa2g, // [32][1024]
                                              float* __restrict__ part){               // [16512][32]
  __shared__ unsigned short sB[32768];  // [32 col][1024 k], chunk c at c^(col&7)
  const int tid = threadIdx.x;
  const int wv = tid >> 6, l = tid & 63;
  const int lm = l & 15, lk = l >> 4;
  #pragma unroll
  for (int j = 0; j < 32; j++){
    unsigned d = (unsigned)(j * 128 + tid) * 16;
    unsigned col = d >> 11;
    unsigned srcC = ((d >> 4) & 127u) ^ (col & 7u);
    const unsigned short* g = Wa2g + col * 1024 + srcC * 8;
    __builtin_amdgcn_global_load_lds((const __attribute__((address_space(1))) void*)g,
                                     (__attribute__((address_space(3))) void*)&sB[d >> 1],
                                     16, 0, 0);
  }
  __syncthreads();
  const int rbase = blockIdx.x * 64 + wv * 32;
  f32x4 acc[2][2] = {};
  for (int kk = 0; kk < 1024; kk += 32){
    s16x8 aF[2], bF[2];
    #pragma unroll
    for (int m = 0; m < 2; m++)
      aF[m] = *(const s16x8*)(H + (size_t)(rbase + m * 16 + lm) * 1024 + kk + lk * 8);
    #pragma unroll
    for (int n = 0; n < 2; n++){
      unsigned col = (unsigned)(n * 16 + lm);
      unsigned c = (unsigned)(kk >> 3) + (unsigned)lk;
      bF[n] = *(const s16x8*)&sB[(col * 2048u + ((c ^ (col & 7u)) << 4)) >> 1];
    }
    #pragma unroll
    for (int m = 0; m < 2; m++){
      #pragma unroll
      for (int n = 0; n < 2; n++)
        acc[m][n] = MFMA16(aF[m], bF[n], acc[m][n], 0, 0, 0);
    }
  }
  #pragma unroll
  for (int m = 0; m < 2; m++){
    #pragma unroll
    for (int r = 0; r < 4; r++){
      int row = rbase + m * 16 + lk * 4 + r;
      #pragma unroll
      for (int n = 0; n < 2; n++)
        part[(size_t)row * 32 + n * 16 + lm] = acc[m][n][r];
    }
  }
}

// ---------------- K4: softmax (from part) + 32x32 matrix chain, scaled by s ----------------
__global__ __launch_bounds__(256) void k_chain(const unsigned short* __restrict__ H,
                                               const float* __restrict__ part,
                                               const float* __restrict__ battn,
                                               float* __restrict__ out){
  const int tid = threadIdx.x;
  const int w = tid >> 6, l = tid & 63;
  const int blk = (blockIdx.x & 7) * 512 + (blockIdx.x >> 3);
  const int pos = blk * 4 + w;
  const int bb = pos >> 11, li = pos & 2047;
  const unsigned short* hbase = H + ((size_t)(bb * LPAD + li) << 10);
  const int col = l & 31;
  const int kh = (l >> 5) << 3;

  const float* prow = part + (size_t)(bb * LPAD + li) * 32;
  float sc[5];
  #pragma unroll
  for (int f = 0; f < 5; f++){
    float a = battn[f];
    #pragma unroll
    for (int k = 0; k < 5; k++)
      a += prow[k * 32 + f * 5 + k];
    sc[f] = (a > 0.f) ? a : 0.01f * a;
  }
  float mx = sc[0];
  #pragma unroll
  for (int f = 1; f < 5; f++) mx = fmaxf(mx, sc[f]);
  float e0 = expf(sc[0] - mx), e1 = expf(sc[1] - mx), e2 = expf(sc[2] - mx),
        e3 = expf(sc[3] - mx), e4 = expf(sc[4] - mx);
  float ssum = e0 + e1 + e2 + e3 + e4;
  float inv = 1.f / ssum;
  float inv2 = inv * inv;
  const float sv = (e0 * e1 * e2 * e3 * e4) * inv2 * inv2 * inv;

  const unsigned short* h4 = hbase + 4 * 1024;
  unsigned q0, q1, q2, q3, q4, q5, q6, q7;
  {
    #define LD2(kk) ((unsigned)h4[(kk) * 32 + col] | ((unsigned)h4[((kk) + 1) * 32 + col] << 16))
    q0 = LD2(kh + 0);  q1 = LD2(kh + 2);  q2 = LD2(kh + 4);  q3 = LD2(kh + 6);
    q4 = LD2(kh + 16); q5 = LD2(kh + 18); q6 = LD2(kh + 20); q7 = LD2(kh + 22);
    #undef LD2
  }
  union { unsigned u[4]; s16x8 v; } ub0, ub1;
  ub0.u[0] = q0; ub0.u[1] = q1; ub0.u[2] = q2; ub0.u[3] = q3;
  ub1.u[0] = q4; ub1.u[1] = q5; ub1.u[2] = q6; ub1.u[3] = q7;
  s16x8 Bf0 = ub0.v, Bf1 = ub1.v;

  f32x16 acc;
  #pragma unroll
  for (int st = 0; st < 4; st++){
    const int km = 3 - st;
    const unsigned short* hA = hbase + (km << 10);
    s16x8 A0 = *(const s16x8*)(hA + col * 32 + kh);
    s16x8 A1 = *(const s16x8*)(hA + col * 32 + kh + 16);
    f32x16 z = {0,0,0,0,0,0,0,0,0,0,0,0,0,0,0,0};
    acc = __builtin_amdgcn_mfma_f32_32x32x16_bf16(A0, Bf0, z,   0, 0, 0);
    acc = __builtin_amdgcn_mfma_f32_32x32x16_bf16(A1, Bf1, acc, 0, 0, 0);
    if (st < 3){
      unsigned d0 = cvt_pk_bf16(acc[0],  acc[1]);
      unsigned d1 = cvt_pk_bf16(acc[2],  acc[3]);
      unsigned d2 = cvt_pk_bf16(acc[4],  acc[5]);
      unsigned d3 = cvt_pk_bf16(acc[6],  acc[7]);
      unsigned d4 = cvt_pk_bf16(acc[8],  acc[9]);
      unsigned d5 = cvt_pk_bf16(acc[10], acc[11]);
      unsigned d6 = cvt_pk_bf16(acc[12], acc[13]);
      unsigned d7 = cvt_pk_bf16(acc[14], acc[15]);
      unsigned p0 = __shfl_xor(d0, 32, 64);
      unsigned p1 = __shfl_xor(d1, 32, 64);
      unsigned p2 = __shfl_xor(d2, 32, 64);
      unsigned p3 = __shfl_xor(d3, 32, 64);
      unsigned p4 = __shfl_xor(d4, 32, 64);
      unsigned p5 = __shfl_xor(d5, 32, 64);
      unsigned p6 = __shfl_xor(d6, 32, 64);
      unsigned p7 = __shfl_xor(d7, 32, 64);
      const bool lo = (l < 32);
      ub0.u[0] = lo ? d0 : p2;  ub0.u[1] = lo ? d1 : p3;
      ub0.u[2] = lo ? p0 : d2;  ub0.u[3] = lo ? p1 : d3;
      ub1.u[0] = lo ? d4 : p6;  ub1.u[1] = lo ? d5 : p7;
      ub1.u[2] = lo ? p4 : d6;  ub1.u[3] = lo ? p5 : d7;
      Bf0 = ub0.v; Bf1 = ub1.v;
    }
  }

  float* ob = out + ((size_t)pos << 10);
  #pragma unroll
  for (int t = 0; t < 16; t++){
    int row = (t & 3) + 8 * (t >> 2) + ((l >> 5) << 2);
    ob[row * 32 + col] = sv * acc[t];
  }
}

// ---------------- launcher ----------------
extern "C" void kernel_launch(void* const* d_in, const int* in_sizes, int n_in,
                              void* d_out, int out_size, void* d_ws, size_t ws_size,
                              hipStream_t stream){
  const float* X  = (const float*)d_in[0];
  const float* Wd = (const float*)d_in[1];
  const float* bd = (const float*)d_in[2];
  const float* Wa = (const float*)d_in[3];
  const float* ba = (const float*)d_in[4];
  float* out = (float*)d_out;

  char* ws = (char*)d_ws;
  unsigned short* Hpad = (unsigned short*)ws;                               // 33,619,968 B
  unsigned short* Wbf  = (unsigned short*)(ws + 33619968);                  // 2,097,152 B
  unsigned short* Wa2g = (unsigned short*)(ws + 33619968 + 2097152);        // 65,536 B
  float*          part = (float*)(ws + 33619968 + 2097152 + 65536);         // 2,113,536 B
  // scratch parked in d_out (consumed by k_gemm2 before k_chain writes):
  unsigned short* Xbf  = (unsigned short*)d_out;                            // [0, 33,554,432)

  k_prep<<<17664, 256, 0, stream>>>(X, Xbf, Wd, Wbf, Hpad, Wa, Wa2g);
  k_gemm2<<<512, 512, 0, stream>>>(Xbf, Wbf, bd, Hpad);
  k_part<<<258, 128, 0, stream>>>(Hpad, Wa2g, part);
  k_chain<<<4096, 256, 0, stream>>>(Hpad, part, ba, out);
}